// Round 4
// baseline (280.308 us; speedup 1.0000x reference)
//
#include <hip/hip_runtime.h>
#include <stdint.h>

// LinearWithLoRA: out = x@W.T + b + 2.0*(x@A.T)@B.T
// x[8192,2048] f32, W[2048,2048] f32, b[2048] f32, A[16,2048] f32, B[2048,16] f32
// out FP32 [8192,2048]  (rounds 1/3 failed by writing bf16 into the fp32 buffer).
//
// Zero-workspace plan:
//  - prep_x: in-place convert each x row to bf16 (packed in first 4KB of the row's
//    8KB storage; row pitch 4096 shorts) and store low = 2.0*(x@A.T) as fp32[16]
//    at float index 1024 of the same row (bytes 4096..4159, untouched by bf16 pack).
//  - prep_w: in-place convert W rows to bf16, pitch 4096 shorts.
//  - gemm_lora: m97 structure (128x128 tile, BK=32, 4 waves, 4x4 acc of
//    16x16x32 bf16 MFMA, global_load_lds width 16, linear LDS) over K=2048,
//    then ONE extra MFMA K-step with [low | 0] x [lora_B | 0] staged in LDS,
//    then bias + FP32 store.

#define SCALING 2.0f

typedef __attribute__((ext_vector_type(8))) __bf16 bf16x8;
typedef __attribute__((ext_vector_type(4))) float f32x4;

static __device__ __forceinline__ unsigned short f2bf(float f) {
  union { float f; unsigned int u; } v; v.f = f;
  return (unsigned short)((v.u + 0x7FFFu + ((v.u >> 16) & 1u)) >> 16);
}

// ---------------- prep_x: 2 rows per block, in-place ----------------
__global__ __launch_bounds__(256) void prep_x(float* __restrict__ x,
                                              const float* __restrict__ lA) {
  const int b = blockIdx.x;          // rows 2b, 2b+1
  const int t = threadIdx.x;
  const int lane = t & 63, w = t >> 6;
  const size_t r0 = (size_t)(2 * b), r1 = r0 + 1;

  float xv[2][8];
  {
    const float* p0 = x + r0 * 2048 + t * 8;
    const float* p1 = x + r1 * 2048 + t * 8;
    float4 a = *(const float4*)p0, c = *(const float4*)(p0 + 4);
    float4 d = *(const float4*)p1, e = *(const float4*)(p1 + 4);
    xv[0][0]=a.x; xv[0][1]=a.y; xv[0][2]=a.z; xv[0][3]=a.w;
    xv[0][4]=c.x; xv[0][5]=c.y; xv[0][6]=c.z; xv[0][7]=c.w;
    xv[1][0]=d.x; xv[1][1]=d.y; xv[1][2]=d.z; xv[1][3]=d.w;
    xv[1][4]=e.x; xv[1][5]=e.y; xv[1][6]=e.z; xv[1][7]=e.w;
  }

  float acc[2][16];
  #pragma unroll
  for (int r = 0; r < 16; ++r) {
    const float* ap = lA + (size_t)r * 2048 + t * 8;
    float4 a0 = *(const float4*)ap, a1 = *(const float4*)(ap + 4);
    float av[8] = {a0.x,a0.y,a0.z,a0.w,a1.x,a1.y,a1.z,a1.w};
    float s0 = 0.f, s1 = 0.f;
    #pragma unroll
    for (int j = 0; j < 8; ++j) { s0 += xv[0][j]*av[j]; s1 += xv[1][j]*av[j]; }
    acc[0][r] = s0; acc[1][r] = s1;
  }
  #pragma unroll
  for (int off = 32; off > 0; off >>= 1)
    #pragma unroll
    for (int i = 0; i < 2; ++i)
      #pragma unroll
      for (int r = 0; r < 16; ++r)
        acc[i][r] += __shfl_xor(acc[i][r], off, 64);

  __shared__ float red[4][2][16];
  if (lane == 0) {
    #pragma unroll
    for (int i = 0; i < 2; ++i)
      #pragma unroll
      for (int r = 0; r < 16; ++r) red[w][i][r] = acc[i][r];
  }
  __syncthreads();   // all reads of x rows done; reduction visible

  // in-place bf16 pack (first 4KB of each 8KB row)
  unsigned short* xs = (unsigned short*)x;
  union { unsigned short h[8]; uint4 v; } pk0, pk1;
  #pragma unroll
  for (int j = 0; j < 8; ++j) { pk0.h[j] = f2bf(xv[0][j]); pk1.h[j] = f2bf(xv[1][j]); }
  *(uint4*)(xs + r0 * 4096 + t * 8) = pk0.v;
  *(uint4*)(xs + r1 * 4096 + t * 8) = pk1.v;

  if (t < 32) {
    const int i = t >> 4, r = t & 15;
    float s = red[0][i][r] + red[1][i][r] + red[2][i][r] + red[3][i][r];
    x[(r0 + i) * 2048 + 1024 + r] = SCALING * s;   // fp32 low, bytes 4096.. of the row
  }
}

// ---------------- prep_w: 1 row per block, in-place ----------------
__global__ __launch_bounds__(256) void prep_w(float* __restrict__ W) {
  const int o = blockIdx.x;
  const int t = threadIdx.x;
  const float* wp = W + (size_t)o * 2048 + t * 8;
  float4 w0 = *(const float4*)wp, w1 = *(const float4*)(wp + 4);
  __syncthreads();   // all reads of this row done before any bf16 store
  union { unsigned short h[8]; uint4 v; } pk;
  pk.h[0]=f2bf(w0.x); pk.h[1]=f2bf(w0.y); pk.h[2]=f2bf(w0.z); pk.h[3]=f2bf(w0.w);
  pk.h[4]=f2bf(w1.x); pk.h[5]=f2bf(w1.y); pk.h[6]=f2bf(w1.z); pk.h[7]=f2bf(w1.w);
  *(uint4*)((unsigned short*)W + (size_t)o * 4096 + t * 8) = pk.v;
}

// ---------------- main GEMM: m97 structure, linear LDS ----------------
#define GLOAD16(gp, lp)                                                        \
  __builtin_amdgcn_global_load_lds(                                            \
      (const __attribute__((address_space(1))) void*)(const void*)(gp),        \
      (__attribute__((address_space(3))) void*)(void*)(lp), 16, 0, 0)

__global__ __launch_bounds__(256) void gemm_lora(
    const unsigned short* __restrict__ Xb,   // bf16, pitch 4096 shorts
    const unsigned short* __restrict__ Wb,   // bf16, pitch 4096 shorts
    const float* __restrict__ xf,            // fp32 view of x (for low)
    const float* __restrict__ lB,            // [2048][16] fp32
    const float* __restrict__ bias, float* __restrict__ out) {
  __shared__ unsigned short As[128 * 32];
  __shared__ unsigned short Bs[128 * 32];
  const int tid = threadIdx.x;
  const int lane = tid & 63;
  const int w = tid >> 6;
  const int wr = w >> 1, wc = w & 1;

  // XCD-chunked bijective blockIdx swizzle (grid=1024, 1024%8==0)
  const int bid = blockIdx.x;
  const int b2 = (bid & 7) * 128 + (bid >> 3);
  const int tn = b2 >> 6;   // 0..15
  const int tm = b2 & 63;   // 0..63
  const size_t row0 = (size_t)tm * 128;
  const size_t col0 = (size_t)tn * 128;

  // staging: wave w fills issues q0,q1 (16 rows x 32 cols = 1KB each) of A and B
  const int q0 = 2 * w, q1 = q0 + 1;
  const int rq = lane >> 2, p = lane & 3;
  const int rl0 = q0 * 16 + rq, rl1 = q1 * 16 + rq;
  const unsigned short* gA0 = Xb + (row0 + rl0) * 4096 + p * 8;
  const unsigned short* gA1 = Xb + (row0 + rl1) * 4096 + p * 8;
  const unsigned short* gB0 = Wb + (col0 + rl0) * 4096 + p * 8;
  const unsigned short* gB1 = Wb + (col0 + rl1) * 4096 + p * 8;
  unsigned short* lA0 = &As[q0 * 512];
  unsigned short* lA1 = &As[q1 * 512];
  unsigned short* lB0 = &Bs[q0 * 512];
  unsigned short* lB1 = &Bs[q1 * 512];

  // fragment read offsets (linear): lane -> row fr within 16-row tile, k-group g
  const int fr = lane & 15, g = lane >> 4;
  int aidx[4], bidx[4];
  #pragma unroll
  for (int m = 0; m < 4; ++m) aidx[m] = (wr * 64 + m * 16 + fr) * 32 + g * 8;
  #pragma unroll
  for (int n = 0; n < 4; ++n) bidx[n] = (wc * 64 + n * 16 + fr) * 32 + g * 8;

  f32x4 acc[4][4];
  #pragma unroll
  for (int m = 0; m < 4; ++m)
    #pragma unroll
    for (int n = 0; n < 4; ++n) acc[m][n] = f32x4{0.f, 0.f, 0.f, 0.f};

  for (int s = 0; s < 64; ++s) {
    const int ko = s * 32;
    GLOAD16(gA0 + ko, lA0);
    GLOAD16(gA1 + ko, lA1);
    GLOAD16(gB0 + ko, lB0);
    GLOAD16(gB1 + ko, lB1);
    __syncthreads();   // compiler drains vmcnt before s_barrier
    bf16x8 av[4], bv[4];
    #pragma unroll
    for (int m = 0; m < 4; ++m) av[m] = *(const bf16x8*)&As[aidx[m]];
    #pragma unroll
    for (int n = 0; n < 4; ++n) bv[n] = *(const bf16x8*)&Bs[bidx[n]];
    #pragma unroll
    for (int m = 0; m < 4; ++m)
      #pragma unroll
      for (int n = 0; n < 4; ++n)
        acc[m][n] = __builtin_amdgcn_mfma_f32_16x16x32_bf16(av[m], bv[n], acc[m][n], 0, 0, 0);
    __syncthreads();
  }

  // ---- LoRA: one extra K-step with [low | 0] x [lora_B | 0] ----
  {
    const int row = tid >> 1, h = tid & 1;   // 128 rows x 2 halves
    const float* lp = xf + (row0 + row) * 2048 + 1024 + h * 8;   // low (already x2)
    float4 l0 = *(const float4*)lp, l1 = *(const float4*)(lp + 4);
    union { unsigned short hh[8]; uint4 v; } pa;
    pa.hh[0]=f2bf(l0.x); pa.hh[1]=f2bf(l0.y); pa.hh[2]=f2bf(l0.z); pa.hh[3]=f2bf(l0.w);
    pa.hh[4]=f2bf(l1.x); pa.hh[5]=f2bf(l1.y); pa.hh[6]=f2bf(l1.z); pa.hh[7]=f2bf(l1.w);
    *(uint4*)&As[row * 32 + h * 8] = pa.v;

    const float* bp = lB + (size_t)(col0 + row) * 16 + h * 8;
    float4 b0 = *(const float4*)bp, b1 = *(const float4*)(bp + 4);
    union { unsigned short hh[8]; uint4 v; } pb;
    pb.hh[0]=f2bf(b0.x); pb.hh[1]=f2bf(b0.y); pb.hh[2]=f2bf(b0.z); pb.hh[3]=f2bf(b0.w);
    pb.hh[4]=f2bf(b1.x); pb.hh[5]=f2bf(b1.y); pb.hh[6]=f2bf(b1.z); pb.hh[7]=f2bf(b1.w);
    *(uint4*)&Bs[row * 32 + h * 8] = pb.v;

    uint4 z; z.x = z.y = z.z = z.w = 0u;
    *(uint4*)&As[row * 32 + 16 + h * 8] = z;
    *(uint4*)&Bs[row * 32 + 16 + h * 8] = z;
    __syncthreads();

    bf16x8 av[4], bv[4];
    #pragma unroll
    for (int m = 0; m < 4; ++m) av[m] = *(const bf16x8*)&As[aidx[m]];
    #pragma unroll
    for (int n = 0; n < 4; ++n) bv[n] = *(const bf16x8*)&Bs[bidx[n]];
    #pragma unroll
    for (int m = 0; m < 4; ++m)
      #pragma unroll
      for (int n = 0; n < 4; ++n)
        acc[m][n] = __builtin_amdgcn_mfma_f32_16x16x32_bf16(av[m], bv[n], acc[m][n], 0, 0, 0);
  }

  // ---- epilogue: + bias, FP32 store. C/D: col=lane&15, row=(lane>>4)*4+j ----
  #pragma unroll
  for (int n = 0; n < 4; ++n) {
    const int gn = (int)col0 + wc * 64 + n * 16 + fr;
    const float bvs = bias[gn];
    #pragma unroll
    for (int m = 0; m < 4; ++m) {
      const int gm0 = (int)row0 + wr * 64 + m * 16 + g * 4;
      #pragma unroll
      for (int j = 0; j < 4; ++j) {
        out[(size_t)(gm0 + j) * 2048 + gn] = acc[m][n][j] + bvs;
      }
    }
  }
}

extern "C" void kernel_launch(void* const* d_in, const int* in_sizes, int n_in,
                              void* d_out, int out_size, void* d_ws, size_t ws_size,
                              hipStream_t stream) {
  float* x  = (float*)d_in[0];
  float* W  = (float*)d_in[1];
  const float* b  = (const float*)d_in[2];
  const float* lA = (const float*)d_in[3];
  const float* lB = (const float*)d_in[4];
  float* out = (float*)d_out;
  (void)d_ws; (void)ws_size;

  prep_x<<<4096, 256, 0, stream>>>(x, lA);
  prep_w<<<2048, 256, 0, stream>>>(W);
  gemm_lora<<<1024, 256, 0, stream>>>((const unsigned short*)x, (const unsigned short*)W,
                                      (const float*)x, lB, b, out);
}

// Round 5
// 249.234 us; speedup vs baseline: 1.1247x; 1.1247x over previous
//
#include <hip/hip_runtime.h>
#include <stdint.h>

// LinearWithLoRA: out = x@W.T + b + 2.0*(x@A.T)@B.T   (out fp32 [8192,2048])
// x[8192,2048] f32, W[2048,2048] f32, b[2048] f32, A[16,2048] f32, B[2048,16] f32
//
// R5 structure:
//  - prep_cvt: ONE kernel, in-place fp32->bf16 convert of x, W, lora_A rows
//    (bf16 packed into first half of each 8KB row; pitch 4096 shorts). Pure
//    BW-bound; the old shuffle-tree x@A.T reduction (~130us of LDS-pipe ops)
//    is deleted.
//  - gemm_lora: m97 128x128 structure over K=2048. NEW: computes
//    P = X_tile @ A.T in-loop via MFMA (wc==0 waves, A-tile staged by wave 0
//    with a 5th global_load_lds), then P (x2) -> LDS -> bf16 A-fragment for the
//    final LoRA K-step against bf16(lora_B). Bias + fp32 store.

#define SCALING 2.0f

typedef __attribute__((ext_vector_type(8))) __bf16 bf16x8;
typedef __attribute__((ext_vector_type(4))) float f32x4;

static __device__ __forceinline__ unsigned short f2bf(float f) {
  union { float f; unsigned int u; } v; v.f = f;
  return (unsigned short)((v.u + 0x7FFFu + ((v.u >> 16) & 1u)) >> 16);
}

// ---- prep: in-place fp32 -> bf16 row convert (row = 2048 floats) ----
// grid: 8192 x-rows, 2048 W-rows, 16 A-rows = 10256 blocks x 256 threads.
__global__ __launch_bounds__(256) void prep_cvt(float* x, float* W, float* A) {
  const int bid = blockIdx.x;
  float* base; size_t row;
  if (bid < 8192)       { base = x; row = (size_t)bid; }
  else if (bid < 10240) { base = W; row = (size_t)(bid - 8192); }
  else                  { base = A; row = (size_t)(bid - 10240); }
  const int t = threadIdx.x;
  const float* src = base + row * 2048 + t * 8;
  float4 v0 = *(const float4*)src;
  float4 v1 = *(const float4*)(src + 4);
  __syncthreads();   // every lane's fp32 reads of this row done before any write
  union { unsigned short h[8]; uint4 v; } pk;
  pk.h[0]=f2bf(v0.x); pk.h[1]=f2bf(v0.y); pk.h[2]=f2bf(v0.z); pk.h[3]=f2bf(v0.w);
  pk.h[4]=f2bf(v1.x); pk.h[5]=f2bf(v1.y); pk.h[6]=f2bf(v1.z); pk.h[7]=f2bf(v1.w);
  *(uint4*)((unsigned short*)base + row * 4096 + t * 8) = pk.v;
}

// ---------------- main GEMM ----------------
#define GLOAD16(gp, lp)                                                        \
  __builtin_amdgcn_global_load_lds(                                            \
      (const __attribute__((address_space(1))) void*)(const void*)(gp),        \
      (__attribute__((address_space(3))) void*)(void*)(lp), 16, 0, 0)

__global__ __launch_bounds__(256) void gemm_lora(
    const unsigned short* __restrict__ Xb,   // bf16, pitch 4096 shorts
    const unsigned short* __restrict__ Wb,   // bf16, pitch 4096 shorts
    const unsigned short* __restrict__ Ab,   // bf16 lora_A, pitch 4096 shorts, 16 rows
    const float* __restrict__ lB,            // [2048][16] fp32
    const float* __restrict__ bias, float* __restrict__ out) {
  __shared__ unsigned short As[128 * 32];
  __shared__ unsigned short Bs[128 * 32];
  __shared__ unsigned short Ps[16 * 32];     // A-tile for P = X@A.T
  const int tid = threadIdx.x;
  const int lane = tid & 63;
  const int w = tid >> 6;
  const int wr = w >> 1, wc = w & 1;

  // XCD-chunked bijective blockIdx swizzle (grid=1024, 1024%8==0)
  const int bid = blockIdx.x;
  const int b2 = (bid & 7) * 128 + (bid >> 3);
  const int tn = b2 >> 6;   // 0..15
  const int tm = b2 & 63;   // 0..63
  const size_t row0 = (size_t)tm * 128;
  const size_t col0 = (size_t)tn * 128;

  // staging: wave w fills issues q0,q1 (16 rows x 32 cols = 1KB each) of A and B
  const int q0 = 2 * w, q1 = q0 + 1;
  const int rq = lane >> 2, p = lane & 3;
  const int rl0 = q0 * 16 + rq, rl1 = q1 * 16 + rq;
  const unsigned short* gA0 = Xb + (row0 + rl0) * 4096 + p * 8;
  const unsigned short* gA1 = Xb + (row0 + rl1) * 4096 + p * 8;
  const unsigned short* gB0 = Wb + (col0 + rl0) * 4096 + p * 8;
  const unsigned short* gB1 = Wb + (col0 + rl1) * 4096 + p * 8;
  // P-tile: 16 rows of Ab x 32 cols = 1KB, staged by wave 0 only
  const unsigned short* gP0 = Ab + (size_t)(lane >> 2) * 4096 + (lane & 3) * 8;
  unsigned short* lA0 = &As[q0 * 512];
  unsigned short* lA1 = &As[q1 * 512];
  unsigned short* lB0 = &Bs[q0 * 512];
  unsigned short* lB1 = &Bs[q1 * 512];

  // fragment read offsets: lane -> row fr within 16-row tile, k-group g
  const int fr = lane & 15, g = lane >> 4;
  int aidx[4], bidx[4];
  #pragma unroll
  for (int m = 0; m < 4; ++m) aidx[m] = (wr * 64 + m * 16 + fr) * 32 + g * 8;
  #pragma unroll
  for (int n = 0; n < 4; ++n) bidx[n] = (wc * 64 + n * 16 + fr) * 32 + g * 8;

  f32x4 acc[4][4];
  f32x4 accP[4];
  #pragma unroll
  for (int m = 0; m < 4; ++m) {
    accP[m] = f32x4{0.f, 0.f, 0.f, 0.f};
    #pragma unroll
    for (int n = 0; n < 4; ++n) acc[m][n] = f32x4{0.f, 0.f, 0.f, 0.f};
  }

  for (int s = 0; s < 64; ++s) {
    const int ko = s * 32;
    GLOAD16(gA0 + ko, lA0);
    GLOAD16(gA1 + ko, lA1);
    GLOAD16(gB0 + ko, lB0);
    GLOAD16(gB1 + ko, lB1);
    if (w == 0) GLOAD16(gP0 + ko, &Ps[0]);
    __syncthreads();   // compiler drains vmcnt before s_barrier
    bf16x8 av[4], bv[4];
    #pragma unroll
    for (int m = 0; m < 4; ++m) av[m] = *(const bf16x8*)&As[aidx[m]];
    #pragma unroll
    for (int n = 0; n < 4; ++n) bv[n] = *(const bf16x8*)&Bs[bidx[n]];
    bf16x8 bvP = *(const bf16x8*)&Ps[fr * 32 + g * 8];
    #pragma unroll
    for (int m = 0; m < 4; ++m)
      #pragma unroll
      for (int n = 0; n < 4; ++n)
        acc[m][n] = __builtin_amdgcn_mfma_f32_16x16x32_bf16(av[m], bv[n], acc[m][n], 0, 0, 0);
    if (wc == 0) {
      #pragma unroll
      for (int m = 0; m < 4; ++m)
        accP[m] = __builtin_amdgcn_mfma_f32_16x16x32_bf16(av[m], bvP, accP[m], 0, 0, 0);
    }
    __syncthreads();
  }

  // ---- LoRA finish: P (x2) -> LDS; lora_B -> bf16 in Bs; one extra K-step ----
  float* P_lds = (float*)As;   // 128 rows x 16 cols fp32 = 8KB, exact As reuse
  if (wc == 0) {
    #pragma unroll
    for (int m = 0; m < 4; ++m)
      #pragma unroll
      for (int j = 0; j < 4; ++j) {
        const int row = wr * 64 + m * 16 + (lane >> 4) * 4 + j;  // C/D: col=lane&15
        P_lds[row * 16 + fr] = SCALING * accP[m][j];
      }
  }
  {
    const int row = tid >> 1, h = tid & 1;   // stage lora_B rows col0..col0+127
    const float* bp = lB + (size_t)(col0 + row) * 16 + h * 8;
    float4 b0 = *(const float4*)bp, b1 = *(const float4*)(bp + 4);
    union { unsigned short hh[8]; uint4 v; } pb;
    pb.hh[0]=f2bf(b0.x); pb.hh[1]=f2bf(b0.y); pb.hh[2]=f2bf(b0.z); pb.hh[3]=f2bf(b0.w);
    pb.hh[4]=f2bf(b1.x); pb.hh[5]=f2bf(b1.y); pb.hh[6]=f2bf(b1.z); pb.hh[7]=f2bf(b1.w);
    *(uint4*)&Bs[row * 32 + h * 8] = pb.v;
    uint4 z; z.x = z.y = z.z = z.w = 0u;
    *(uint4*)&Bs[row * 32 + 16 + h * 8] = z;   // zero pad k=16..31
  }
  __syncthreads();

  {
    bf16x8 av2[4], bv2[4];
    #pragma unroll
    for (int m = 0; m < 4; ++m) {
      union { unsigned short hh[8]; bf16x8 v; } pa;
      if (g < 2) {
        const float* pr = &P_lds[(wr * 64 + m * 16 + fr) * 16 + g * 8];
        #pragma unroll
        for (int jj = 0; jj < 8; ++jj) pa.hh[jj] = f2bf(pr[jj]);
      } else {
        #pragma unroll
        for (int jj = 0; jj < 8; ++jj) pa.hh[jj] = 0;
      }
      av2[m] = pa.v;
    }
    #pragma unroll
    for (int n = 0; n < 4; ++n) bv2[n] = *(const bf16x8*)&Bs[bidx[n]];
    #pragma unroll
    for (int m = 0; m < 4; ++m)
      #pragma unroll
      for (int n = 0; n < 4; ++n)
        acc[m][n] = __builtin_amdgcn_mfma_f32_16x16x32_bf16(av2[m], bv2[n], acc[m][n], 0, 0, 0);
  }

  // ---- epilogue: + bias, FP32 store. C/D: col=lane&15, row=(lane>>4)*4+j ----
  #pragma unroll
  for (int n = 0; n < 4; ++n) {
    const int gn = (int)col0 + wc * 64 + n * 16 + fr;
    const float bvs = bias[gn];
    #pragma unroll
    for (int m = 0; m < 4; ++m) {
      const int gm0 = (int)row0 + wr * 64 + m * 16 + g * 4;
      #pragma unroll
      for (int j = 0; j < 4; ++j) {
        out[(size_t)(gm0 + j) * 2048 + gn] = acc[m][n][j] + bvs;
      }
    }
  }
}

extern "C" void kernel_launch(void* const* d_in, const int* in_sizes, int n_in,
                              void* d_out, int out_size, void* d_ws, size_t ws_size,
                              hipStream_t stream) {
  float* x  = (float*)d_in[0];
  float* W  = (float*)d_in[1];
  const float* b  = (const float*)d_in[2];
  float* lA = (float*)d_in[3];
  const float* lB = (const float*)d_in[4];
  float* out = (float*)d_out;
  (void)d_ws; (void)ws_size;

  prep_cvt<<<10256, 256, 0, stream>>>(x, W, lA);
  gemm_lora<<<1024, 256, 0, stream>>>((const unsigned short*)x, (const unsigned short*)W,
                                      (const unsigned short*)lA, lB, b, out);
}